// Round 1
// baseline (387.194 us; speedup 1.0000x reference)
//
#include <hip/hip_runtime.h>
#include <hip/hip_bf16.h>
#include <stdint.h>

#define B_ 2
#define D_ 128
#define H_ 512
#define W_ 512
#define G_ 60
#define NQ_ 7200
#define BORDER_ 16
#define STEP_ 8

typedef __attribute__((ext_vector_type(8))) short short8;
typedef __attribute__((ext_vector_type(4))) float f32x4;

__device__ __forceinline__ float bf_lo(uint32_t u){ return __builtin_bit_cast(float, u << 16); }
__device__ __forceinline__ float bf_hi(uint32_t u){ return __builtin_bit_cast(float, u & 0xffff0000u); }

__device__ __forceinline__ uint32_t pack2bf(float lo, float hi){
  uint16_t l = __builtin_bit_cast(uint16_t, __float2bfloat16(lo));
  uint16_t h = __builtin_bit_cast(uint16_t, __float2bfloat16(hi));
  return (uint32_t)l | ((uint32_t)h << 16);
}

// ---------------- feat2 (B,D,H,W) f32 -> (B,H,W,D) bf16 ----------------
__global__ __launch_bounds__(256) void transpose_k(const float* __restrict__ src,
                                                   __hip_bfloat16* __restrict__ dst){
  __shared__ float lds[64][129];
  int b = blockIdx.z, y = blockIdx.y, x0 = blockIdx.x * 64;
  int tid = threadIdx.x;
  int xl = tid & 63, dq = tid >> 6;
  size_t base_in = (((size_t)b * D_) * H_ + y) * W_ + x0;
  #pragma unroll
  for (int it = 0; it < 32; ++it){
    int d = it * 4 + dq;
    lds[xl][d] = src[base_in + (size_t)d * H_ * W_ + xl];
  }
  __syncthreads();
  int k = tid & 63;       // d-pair index
  int xw = tid >> 6;      // 0..3
  size_t pixbase = (((size_t)b * H_ + y) * W_ + x0);
  #pragma unroll
  for (int it = 0; it < 16; ++it){
    int xl2 = xw + it * 4;
    uint32_t u = pack2bf(lds[xl2][2 * k], lds[xl2][2 * k + 1]);
    *reinterpret_cast<uint32_t*>(dst + (pixbase + xl2) * D_ + 2 * k) = u;
  }
}

// ---------------- per-query prep: f1, d3, xy2-derived tables, mask, qconf ----------------
template<bool USE_T>
__global__ __launch_bounds__(256) void prep_k(
    const float* __restrict__ feat1, const float* __restrict__ feat2,
    const __hip_bfloat16* __restrict__ f2t,
    const float* __restrict__ conf1, const float* __restrict__ aflow,
    __hip_bfloat16* __restrict__ f1o, __hip_bfloat16* __restrict__ d3o,
    float2* __restrict__ qxy, float2* __restrict__ dxy,
    float* __restrict__ omask, float* __restrict__ oqconf)
{
  int n = blockIdx.x;
  int b = n / (G_ * G_); int r = n % (G_ * G_);
  int iy = r / G_, ix = r % G_;
  int y1 = BORDER_ + iy * STEP_, x1 = BORDER_ + ix * STEP_;
  int tid = threadIdx.x;
  size_t pix = ((size_t)b * H_ + y1) * W_ + x1;
  if (tid < 64){
    int d = tid * 2;
    size_t o = (((size_t)b * D_ + d) * H_ + y1) * W_ + x1;
    float lo = feat1[o];
    float hi = feat1[o + (size_t)H_ * W_];
    *reinterpret_cast<uint32_t*>(f1o + (size_t)n * D_ + d) = pack2bf(lo, hi);
  } else if (tid < 128){
    int d = (tid - 64) * 2;
    uint32_t u;
    if (USE_T){
      u = *reinterpret_cast<const uint32_t*>(f2t + pix * D_ + d);
    } else {
      size_t o = (((size_t)b * D_ + d) * H_ + y1) * W_ + x1;
      u = pack2bf(feat2[o], feat2[o + (size_t)H_ * W_]);
    }
    *reinterpret_cast<uint32_t*>(d3o + (size_t)n * D_ + d) = u;
  } else if (tid == 128){
    float ax = aflow[(((size_t)b * 2 + 0) * H_ + y1) * W_ + x1];
    float ay = aflow[(((size_t)b * 2 + 1) * H_ + y1) * W_ + x1];
    int x2 = (int)(ax + 0.5f);   // trunc toward zero, matches astype(int32)
    int y2 = (int)(ay + 0.5f);
    omask[n] = (x2 >= 0 && y2 >= 0 && x2 < W_ && y2 < H_) ? 1.0f : 0.0f;
    oqconf[n] = conf1[pix];
    float bs = 512.0f * (float)b;
    qxy[n] = make_float2((float)x2 + bs, (float)y2 + bs);
    dxy[n] = make_float2((float)x1 + bs, (float)y1 + bs);
  }
}

// ---------------- pos/neg neighbor scores (cols 0..P+NN-1) ----------------
template<bool USE_T>
__global__ __launch_bounds__(256) void posneg_k(
    const __hip_bfloat16* __restrict__ f1o,
    const __hip_bfloat16* __restrict__ f2t,
    const float* __restrict__ feat2,
    const float* __restrict__ aflow,
    const int* __restrict__ pos, const int* __restrict__ neg,
    int P, int NN, float* __restrict__ out, int NCOL, size_t GTOFF)
{
  int n = blockIdx.x;
  int b = n / (G_ * G_); int r = n % (G_ * G_);
  int iy = r / G_, ix = r % G_;
  int y1 = BORDER_ + iy * STEP_, x1 = BORDER_ + ix * STEP_;
  int tid = threadIdx.x;
  int l16 = tid & 15, grp = tid >> 4;   // 16 groups of 16 lanes

  const uint4 av = *reinterpret_cast<const uint4*>(f1o + (size_t)n * D_ + l16 * 8);
  float a[8];
  a[0] = bf_lo(av.x); a[1] = bf_hi(av.x); a[2] = bf_lo(av.y); a[3] = bf_hi(av.y);
  a[4] = bf_lo(av.z); a[5] = bf_hi(av.z); a[6] = bf_lo(av.w); a[7] = bf_hi(av.w);

  float ax = aflow[(((size_t)b * 2 + 0) * H_ + y1) * W_ + x1];
  float ay = aflow[(((size_t)b * 2 + 1) * H_ + y1) * W_ + x1];
  int x2 = (int)(ax + 0.5f), y2 = (int)(ay + 0.5f);

  int NP = P + NN;
  for (int p0 = 0; p0 < NP; p0 += 16){
    int p = p0 + grp;
    float s = 0.0f;
    if (p < NP){
      int ox, oy;
      if (p < P){ ox = pos[p]; oy = pos[P + p]; }
      else      { ox = neg[p - P]; oy = neg[NN + p - P]; }
      int px = min(max(x2 + ox, 0), W_ - 1);
      int py = min(max(y2 + oy, 0), H_ - 1);
      if (USE_T){
        const uint4 v = *reinterpret_cast<const uint4*>(
            f2t + (((size_t)b * H_ + py) * W_ + px) * D_ + l16 * 8);
        s = a[0]*bf_lo(v.x) + a[1]*bf_hi(v.x) + a[2]*bf_lo(v.y) + a[3]*bf_hi(v.y)
          + a[4]*bf_lo(v.z) + a[5]*bf_hi(v.z) + a[6]*bf_lo(v.w) + a[7]*bf_hi(v.w);
      } else {
        size_t o = (((size_t)b * D_ + l16 * 8) * H_ + py) * W_ + px;
        #pragma unroll
        for (int j = 0; j < 8; ++j) s += a[j] * feat2[o + (size_t)j * H_ * W_];
      }
    }
    s += __shfl_xor(s, 1); s += __shfl_xor(s, 2);
    s += __shfl_xor(s, 4); s += __shfl_xor(s, 8);
    if (p < NP && l16 == 0){
      size_t idx = (size_t)n * NCOL + p;
      out[idx] = s;
      out[GTOFF + idx] = (p < P) ? 1.0f : 0.0f;
    }
  }
}

// ---------------- dscores GEMM (cols CB..CB+7199) + distance mask + gt zeros ----------------
__global__ __launch_bounds__(256) void gemm_k(
    const __hip_bfloat16* __restrict__ f1o, const __hip_bfloat16* __restrict__ d3o,
    const float2* __restrict__ qxy, const float2* __restrict__ dxy,
    float* __restrict__ out, int NCOL, size_t GTOFF, int CB)
{
  int m0 = blockIdx.y * 96, n0 = blockIdx.x * 96;
  int tid = threadIdx.x;
  int lane = tid & 63, wid = tid >> 6;
  int wr = wid >> 1, wc = wid & 1;      // 2x2 waves, each 48x48
  int r16 = lane & 15, kg = lane >> 4;  // fragment row/col + k-group

  f32x4 acc[3][3] = {};
  #pragma unroll
  for (int ks = 0; ks < 4; ++ks){
    int k0 = ks * 32 + kg * 8;
    short8 af[3], br[3];
    #pragma unroll
    for (int i = 0; i < 3; ++i){
      int m = m0 + wr * 48 + i * 16 + r16;
      af[i] = *reinterpret_cast<const short8*>(f1o + (size_t)m * D_ + k0);
      int nn = n0 + wc * 48 + i * 16 + r16;
      br[i] = *reinterpret_cast<const short8*>(d3o + (size_t)nn * D_ + k0);
    }
    #pragma unroll
    for (int i = 0; i < 3; ++i)
      #pragma unroll
      for (int j = 0; j < 3; ++j)
        acc[i][j] = __builtin_amdgcn_mfma_f32_16x16x32_bf16(af[i], br[j], acc[i][j], 0, 0, 0);
  }

  float qx[3][4], qy[3][4];
  #pragma unroll
  for (int i = 0; i < 3; ++i)
    #pragma unroll
    for (int rr = 0; rr < 4; ++rr){
      int m = m0 + wr * 48 + i * 16 + (lane >> 4) * 4 + rr;
      float2 q = qxy[m];
      qx[i][rr] = q.x; qy[i][rr] = q.y;
    }

  #pragma unroll
  for (int j = 0; j < 3; ++j){
    int nn = n0 + wc * 48 + j * 16 + r16;
    float2 dc = dxy[nn];
    #pragma unroll
    for (int i = 0; i < 3; ++i){
      int mbase = m0 + wr * 48 + i * 16 + (lane >> 4) * 4;
      #pragma unroll
      for (int rr = 0; rr < 4; ++rr){
        float v = acc[i][j][rr];
        float ddx = qx[i][rr] - dc.x, ddy = qy[i][rr] - dc.y;
        if (ddx * ddx + ddy * ddy < 16.0f) v = 0.0f;
        size_t idx = (size_t)(mbase + rr) * NCOL + CB + nn;
        out[idx] = v;
        out[GTOFF + idx] = 0.0f;
      }
    }
  }
}

extern "C" void kernel_launch(void* const* d_in, const int* in_sizes, int n_in,
                              void* d_out, int out_size, void* d_ws, size_t ws_size,
                              hipStream_t stream)
{
  const float* feat1 = (const float*)d_in[0];
  const float* feat2 = (const float*)d_in[1];
  const float* conf1 = (const float*)d_in[2];
  const float* aflow = (const float*)d_in[4];
  const int* pos = (const int*)d_in[5];
  const int* neg = (const int*)d_in[6];
  int P = in_sizes[5] / 2, NN = in_sizes[6] / 2;
  int NCOL = P + NN + NQ_;
  size_t GTOFF = (size_t)NQ_ * (size_t)NCOL;
  float* out = (float*)d_out;

  char* ws = (char*)d_ws;
  __hip_bfloat16* f1o = (__hip_bfloat16*)ws;                     // 7200*128*2 = 1,843,200
  __hip_bfloat16* d3o = (__hip_bfloat16*)(ws + 1843200);         // 1,843,200
  float2* qxy = (float2*)(ws + 3686400);                         // 57,600
  float2* dxy = (float2*)(ws + 3744000);                         // 57,600
  __hip_bfloat16* f2t = (__hip_bfloat16*)(ws + 3801600);         // 134,217,728
  size_t needT = 3801600ull + (size_t)B_ * H_ * W_ * D_ * 2;
  bool useT = ws_size >= needT;

  float* omask  = out + 2 * GTOFF;
  float* oqconf = omask + NQ_;

  if (useT){
    transpose_k<<<dim3(W_ / 64, H_, B_), 256, 0, stream>>>(feat2, f2t);
    prep_k<true><<<NQ_, 256, 0, stream>>>(feat1, feat2, f2t, conf1, aflow,
                                          f1o, d3o, qxy, dxy, omask, oqconf);
    posneg_k<true><<<NQ_, 256, 0, stream>>>(f1o, f2t, feat2, aflow, pos, neg,
                                            P, NN, out, NCOL, GTOFF);
  } else {
    prep_k<false><<<NQ_, 256, 0, stream>>>(feat1, feat2, f2t, conf1, aflow,
                                           f1o, d3o, qxy, dxy, omask, oqconf);
    posneg_k<false><<<NQ_, 256, 0, stream>>>(f1o, f2t, feat2, aflow, pos, neg,
                                             P, NN, out, NCOL, GTOFF);
  }
  gemm_k<<<dim3(NQ_ / 96, NQ_ / 96), 256, 0, stream>>>(f1o, d3o, qxy, dxy,
                                                       out, NCOL, GTOFF, P + NN);
}

// Round 2
// 363.485 us; speedup vs baseline: 1.0652x; 1.0652x over previous
//
#include <hip/hip_runtime.h>
#include <hip/hip_bf16.h>
#include <stdint.h>

#define B_ 2
#define D_ 128
#define H_ 512
#define W_ 512
#define G_ 60
#define NQ_ 7200
#define BORDER_ 16
#define STEP_ 8

typedef __attribute__((ext_vector_type(8))) short short8;
typedef __attribute__((ext_vector_type(4))) float f32x4;
typedef float f32x4u __attribute__((ext_vector_type(4), aligned(4)));

__device__ __forceinline__ float bf_lo(uint32_t u){ return __builtin_bit_cast(float, u << 16); }
__device__ __forceinline__ float bf_hi(uint32_t u){ return __builtin_bit_cast(float, u & 0xffff0000u); }

__device__ __forceinline__ uint32_t pack2bf(float lo, float hi){
  uint16_t l = __builtin_bit_cast(uint16_t, __float2bfloat16(lo));
  uint16_t h = __builtin_bit_cast(uint16_t, __float2bfloat16(hi));
  return (uint32_t)l | ((uint32_t)h << 16);
}

// ---------------- gt region zero-fill (aligned float4 nt stream) ----------------
__global__ __launch_bounds__(256) void gtzero_k(f32x4* __restrict__ gt, size_t n4){
  size_t i = (size_t)blockIdx.x * 256 + threadIdx.x;
  size_t stride = (size_t)gridDim.x * 256;
  f32x4 z = {0.f, 0.f, 0.f, 0.f};
  for (; i < n4; i += stride)
    __builtin_nontemporal_store(z, gt + i);
}

// ---------------- feat2 (B,D,H,W) f32 -> (B,H,W,D) bf16 ----------------
__global__ __launch_bounds__(256) void transpose_k(const float* __restrict__ src,
                                                   __hip_bfloat16* __restrict__ dst){
  // LDS layout: [e][x], e = d-pair index 0..63, x = pixel 0..63, pad 65 (2-way banks, free)
  __shared__ uint32_t lds2[64][65];
  int b = blockIdx.z, y = blockIdx.y, x0 = blockIdx.x * 64;
  int tid = threadIdx.x;
  size_t plane = (size_t)H_ * W_;

  int xq = tid & 15;        // x-quad (4 floats)
  int eg = tid >> 4;        // 0..15
  size_t base_in = (((size_t)b * D_) * H_ + y) * W_ + x0 + 4 * xq;
  #pragma unroll
  for (int it = 0; it < 4; ++it){
    int e = eg + 16 * it;   // d-pair 0..63
    float4 lo = *reinterpret_cast<const float4*>(src + base_in + (size_t)(2 * e) * plane);
    float4 hi = *reinterpret_cast<const float4*>(src + base_in + (size_t)(2 * e + 1) * plane);
    lds2[e][4 * xq + 0] = pack2bf(lo.x, hi.x);
    lds2[e][4 * xq + 1] = pack2bf(lo.y, hi.y);
    lds2[e][4 * xq + 2] = pack2bf(lo.z, hi.z);
    lds2[e][4 * xq + 3] = pack2bf(lo.w, hi.w);
  }
  __syncthreads();

  int eq = tid & 15;        // u32-quad within a pixel's 64-u32 row
  int xb = tid >> 4;        // 0..15
  size_t pixbase = (((size_t)b * H_ + y) * W_ + x0);
  #pragma unroll
  for (int it = 0; it < 4; ++it){
    int x = xb + 16 * it;
    uint4 v;
    v.x = lds2[4 * eq + 0][x];
    v.y = lds2[4 * eq + 1][x];
    v.z = lds2[4 * eq + 2][x];
    v.w = lds2[4 * eq + 3][x];
    *reinterpret_cast<uint4*>(dst + (pixbase + x) * D_ + 8 * eq) = v;
  }
}

// ---------------- per-query prep: f1, d3, xy tables, mask, qconf ----------------
template<bool USE_T>
__global__ __launch_bounds__(128) void prep_k(
    const float* __restrict__ feat1, const float* __restrict__ feat2,
    const __hip_bfloat16* __restrict__ f2t,
    const float* __restrict__ conf1, const float* __restrict__ aflow,
    __hip_bfloat16* __restrict__ f1o, __hip_bfloat16* __restrict__ d3o,
    float2* __restrict__ qxy, float2* __restrict__ dxy,
    float* __restrict__ omask, float* __restrict__ oqconf)
{
  int n = blockIdx.x;
  int b = n / (G_ * G_); int r = n % (G_ * G_);
  int iy = r / G_, ix = r % G_;
  int y1 = BORDER_ + iy * STEP_, x1 = BORDER_ + ix * STEP_;
  int tid = threadIdx.x;
  size_t pix = ((size_t)b * H_ + y1) * W_ + x1;
  if (tid < 64){
    int d = tid * 2;
    size_t o = (((size_t)b * D_ + d) * H_ + y1) * W_ + x1;
    float lo = feat1[o];
    float hi = feat1[o + (size_t)H_ * W_];
    *reinterpret_cast<uint32_t*>(f1o + (size_t)n * D_ + d) = pack2bf(lo, hi);
    if (tid == 0){
      float ax = aflow[(((size_t)b * 2 + 0) * H_ + y1) * W_ + x1];
      float ay = aflow[(((size_t)b * 2 + 1) * H_ + y1) * W_ + x1];
      int x2 = (int)(ax + 0.5f);   // trunc toward zero == astype(int32)
      int y2 = (int)(ay + 0.5f);
      omask[n] = (x2 >= 0 && y2 >= 0 && x2 < W_ && y2 < H_) ? 1.0f : 0.0f;
      oqconf[n] = conf1[pix];
      float bs = 512.0f * (float)b;
      qxy[n] = make_float2((float)x2 + bs, (float)y2 + bs);
      dxy[n] = make_float2((float)x1 + bs, (float)y1 + bs);
    }
  } else {
    int d = (tid - 64) * 2;
    uint32_t u;
    if (USE_T){
      u = *reinterpret_cast<const uint32_t*>(f2t + pix * D_ + d);
    } else {
      size_t o = (((size_t)b * D_ + d) * H_ + y1) * W_ + x1;
      u = pack2bf(feat2[o], feat2[o + (size_t)H_ * W_]);
    }
    *reinterpret_cast<uint32_t*>(d3o + (size_t)n * D_ + d) = u;
  }
}

// ---------------- pos/neg neighbor scores + gt cols 0..P+NN-1 ----------------
template<bool USE_T>
__global__ __launch_bounds__(256) void posneg_k(
    const __hip_bfloat16* __restrict__ f1o,
    const __hip_bfloat16* __restrict__ f2t,
    const float* __restrict__ feat2,
    const float* __restrict__ aflow,
    const int* __restrict__ pos, const int* __restrict__ neg,
    int P, int NN, float* __restrict__ out, int NCOL, size_t GTOFF)
{
  int n = blockIdx.x;
  int b = n / (G_ * G_); int r = n % (G_ * G_);
  int iy = r / G_, ix = r % G_;
  int y1 = BORDER_ + iy * STEP_, x1 = BORDER_ + ix * STEP_;
  int tid = threadIdx.x;
  int l16 = tid & 15, grp = tid >> 4;

  const uint4 av = *reinterpret_cast<const uint4*>(f1o + (size_t)n * D_ + l16 * 8);
  float a[8];
  a[0] = bf_lo(av.x); a[1] = bf_hi(av.x); a[2] = bf_lo(av.y); a[3] = bf_hi(av.y);
  a[4] = bf_lo(av.z); a[5] = bf_hi(av.z); a[6] = bf_lo(av.w); a[7] = bf_hi(av.w);

  float ax = aflow[(((size_t)b * 2 + 0) * H_ + y1) * W_ + x1];
  float ay = aflow[(((size_t)b * 2 + 1) * H_ + y1) * W_ + x1];
  int x2 = (int)(ax + 0.5f), y2 = (int)(ay + 0.5f);

  int NP = P + NN;
  for (int p0 = 0; p0 < NP; p0 += 16){
    int p = p0 + grp;
    float s = 0.0f;
    if (p < NP){
      int ox, oy;
      if (p < P){ ox = pos[p]; oy = pos[P + p]; }
      else      { ox = neg[p - P]; oy = neg[NN + p - P]; }
      int px = min(max(x2 + ox, 0), W_ - 1);
      int py = min(max(y2 + oy, 0), H_ - 1);
      if (USE_T){
        const uint4 v = *reinterpret_cast<const uint4*>(
            f2t + (((size_t)b * H_ + py) * W_ + px) * D_ + l16 * 8);
        s = a[0]*bf_lo(v.x) + a[1]*bf_hi(v.x) + a[2]*bf_lo(v.y) + a[3]*bf_hi(v.y)
          + a[4]*bf_lo(v.z) + a[5]*bf_hi(v.z) + a[6]*bf_lo(v.w) + a[7]*bf_hi(v.w);
      } else {
        size_t o = (((size_t)b * D_ + l16 * 8) * H_ + py) * W_ + px;
        #pragma unroll
        for (int j = 0; j < 8; ++j) s += a[j] * feat2[o + (size_t)j * H_ * W_];
      }
    }
    s += __shfl_xor(s, 1); s += __shfl_xor(s, 2);
    s += __shfl_xor(s, 4); s += __shfl_xor(s, 8);
    if (p < NP && l16 == 0){
      size_t idx = (size_t)n * NCOL + p;
      out[idx] = s;
      out[GTOFF + idx] = (p < P) ? 1.0f : 0.0f;   // gt interior already zeroed
    }
  }
}

// ---------------- dscores GEMM, swapped operands -> float4 col-contiguous stores ----
__global__ __launch_bounds__(256) void gemm_k(
    const __hip_bfloat16* __restrict__ f1o, const __hip_bfloat16* __restrict__ d3o,
    const float2* __restrict__ qxy, const float2* __restrict__ dxy,
    float* __restrict__ out, int NCOL, int CB)
{
  int m0 = blockIdx.y * 96, n0 = blockIdx.x * 96;
  int tid = threadIdx.x;
  int lane = tid & 63, wid = tid >> 6;
  int wr = wid >> 1, wc = wid & 1;      // 2x2 waves, each 48x48
  int r16 = lane & 15, kg = lane >> 4;

  f32x4 acc[3][3] = {};   // acc[j][i]: rows = n-local, cols = m-local
  #pragma unroll
  for (int ks = 0; ks < 4; ++ks){
    int k0 = ks * 32 + kg * 8;
    short8 af[3], br[3];
    #pragma unroll
    for (int i = 0; i < 3; ++i){
      int m = m0 + wr * 48 + i * 16 + r16;
      af[i] = *reinterpret_cast<const short8*>(f1o + (size_t)m * D_ + k0);
      int nn = n0 + wc * 48 + i * 16 + r16;
      br[i] = *reinterpret_cast<const short8*>(d3o + (size_t)nn * D_ + k0);
    }
    #pragma unroll
    for (int j = 0; j < 3; ++j)
      #pragma unroll
      for (int i = 0; i < 3; ++i)
        acc[j][i] = __builtin_amdgcn_mfma_f32_16x16x32_bf16(br[j], af[i], acc[j][i], 0, 0, 0);
  }

  // lane holds scores[m = ..+i*16+r16][n = ..+j*16+kg*4 + v], v=0..3 (contiguous cols)
  #pragma unroll
  for (int i = 0; i < 3; ++i){
    int m = m0 + wr * 48 + i * 16 + r16;
    float2 q = qxy[m];
    size_t rowoff = (size_t)m * NCOL + CB;
    #pragma unroll
    for (int j = 0; j < 3; ++j){
      int nb = n0 + wc * 48 + j * 16 + kg * 4;
      f32x4 dA = *reinterpret_cast<const f32x4*>(dxy + nb);       // (x,y) of nb, nb+1
      f32x4 dB = *reinterpret_cast<const f32x4*>(dxy + nb + 2);   // (x,y) of nb+2, nb+3
      f32x4 v = acc[j][i];
      float dx0 = q.x - dA[0], dy0 = q.y - dA[1];
      float dx1 = q.x - dA[2], dy1 = q.y - dA[3];
      float dx2 = q.x - dB[0], dy2 = q.y - dB[1];
      float dx3 = q.x - dB[2], dy3 = q.y - dB[3];
      if (dx0 * dx0 + dy0 * dy0 < 16.0f) v[0] = 0.0f;
      if (dx1 * dx1 + dy1 * dy1 < 16.0f) v[1] = 0.0f;
      if (dx2 * dx2 + dy2 * dy2 < 16.0f) v[2] = 0.0f;
      if (dx3 * dx3 + dy3 * dy3 < 16.0f) v[3] = 0.0f;
      __builtin_nontemporal_store((f32x4u)v, reinterpret_cast<f32x4u*>(out + rowoff + nb));
    }
  }
}

extern "C" void kernel_launch(void* const* d_in, const int* in_sizes, int n_in,
                              void* d_out, int out_size, void* d_ws, size_t ws_size,
                              hipStream_t stream)
{
  const float* feat1 = (const float*)d_in[0];
  const float* feat2 = (const float*)d_in[1];
  const float* conf1 = (const float*)d_in[2];
  const float* aflow = (const float*)d_in[4];
  const int* pos = (const int*)d_in[5];
  const int* neg = (const int*)d_in[6];
  int P = in_sizes[5] / 2, NN = in_sizes[6] / 2;
  int NCOL = P + NN + NQ_;
  size_t GTOFF = (size_t)NQ_ * (size_t)NCOL;
  float* out = (float*)d_out;

  char* ws = (char*)d_ws;
  __hip_bfloat16* f1o = (__hip_bfloat16*)ws;                     // 1,843,200 B
  __hip_bfloat16* d3o = (__hip_bfloat16*)(ws + 1843200);         // 1,843,200 B
  float2* qxy = (float2*)(ws + 3686400);                         // 57,600 B
  float2* dxy = (float2*)(ws + 3744000);                         // 57,600 B
  __hip_bfloat16* f2t = (__hip_bfloat16*)(ws + 3801600);         // 134,217,728 B
  size_t needT = 3801600ull + (size_t)B_ * H_ * W_ * D_ * 2;
  bool useT = ws_size >= needT;

  float* omask  = out + 2 * GTOFF;
  float* oqconf = omask + NQ_;

  // 1. zero the whole gt region (posneg overwrites cols 0..P+NN-1 afterwards)
  gtzero_k<<<2048, 256, 0, stream>>>((f32x4*)(out + GTOFF), GTOFF / 4);

  if (useT){
    transpose_k<<<dim3(W_ / 64, H_, B_), 256, 0, stream>>>(feat2, f2t);
    prep_k<true><<<NQ_, 128, 0, stream>>>(feat1, feat2, f2t, conf1, aflow,
                                          f1o, d3o, qxy, dxy, omask, oqconf);
    posneg_k<true><<<NQ_, 256, 0, stream>>>(f1o, f2t, feat2, aflow, pos, neg,
                                            P, NN, out, NCOL, GTOFF);
  } else {
    prep_k<false><<<NQ_, 128, 0, stream>>>(feat1, feat2, f2t, conf1, aflow,
                                           f1o, d3o, qxy, dxy, omask, oqconf);
    posneg_k<false><<<NQ_, 256, 0, stream>>>(f1o, f2t, feat2, aflow, pos, neg,
                                             P, NN, out, NCOL, GTOFF);
  }
  gemm_k<<<dim3(NQ_ / 96, NQ_ / 96), 256, 0, stream>>>(f1o, d3o, qxy, dxy,
                                                       out, NCOL, P + NN);
}